// Round 7
// baseline (9203.805 us; speedup 1.0000x reference)
//
#include <hip/hip_runtime.h>
#include <math.h>

#define B_ 64
#define S_ 512
#define I_ 300
#define H_ 512
#define G_ 2048   // 4*H
#define T_ 25
#define K_ 812    // I_ + H_
#define KQ_ 203   // K_/4 float4 groups per weight row
#define IQ_ 75    // I_/4
#define HQ_ 128   // H_/4

// ---------------- workspace layout (float elements) ----------------
static constexpr size_t SZ_XT   = (size_t)S_ * I_ * B_;        // 9,830,400
static constexpr size_t OFS_XT  = 0;                            // xt4 [s][i4][b][4]
static constexpr size_t OFS_XRT = OFS_XT + SZ_XT;               // xrt4 reversed
static constexpr size_t SZ_WC   = (size_t)2 * G_ * K_;          // 3,325,952
static constexpr size_t OFS_WC  = OFS_XRT + SZ_XT;              // w4 [dir][u][g][k4][4]
static constexpr size_t OFS_H0  = OFS_WC + SZ_WC;               // h [dir][u][b]
static constexpr size_t OFS_H1  = OFS_H0 + (size_t)2 * H_ * B_;
static constexpr size_t OFS_C   = OFS_H1 + (size_t)2 * H_ * B_; // unused (c in regs)
static constexpr size_t OFS_YF  = OFS_C + (size_t)2 * H_ * B_;  // [s][h][b]
static constexpr size_t SZ_Y    = (size_t)S_ * H_ * B_;         // 16,777,216
static constexpr size_t OFS_YB  = OFS_YF + SZ_Y;
static constexpr size_t SZ_L    = (size_t)B_ * S_ * T_;         // 819,200
static constexpr size_t OFS_L1  = OFS_YB + SZ_Y;
static constexpr size_t OFS_L2  = OFS_L1 + SZ_L;
static constexpr size_t OFS_LEN = OFS_L2 + SZ_L;   // int32[64]
static constexpr size_t OFS_LLH = OFS_LEN + 64;    // float[64]
static constexpr size_t OFS_CNT = OFS_LLH + 64;    // int32[64] (2 used, 128B apart)

// output layout (float elements in d_out)
static constexpr size_t OFF_LOGITS = 1;
static constexpr size_t OFF_TAGS   = 1 + SZ_L;
static constexpr size_t OFF_MASK   = OFF_TAGS + (size_t)B_ * S_;

// ---------------- small utility kernels ----------------
__global__ void k_lengths(const int* __restrict__ am, int* __restrict__ len) {
    int b = threadIdx.x;
    int sum = 0;
    for (int s = 0; s < S_; ++s) sum += am[b * S_ + s];
    len[b] = sum;
}

__global__ void k_zero(float* __restrict__ p, int n) {
    int idx = blockIdx.x * 256 + threadIdx.x;
    if (idx < n) p[idx] = 0.f;
}

// w4[dir][u(512)][g(4)][k4(203)][4] = [W_ih row | W_hh row] quad-packed.
__global__ void k_prep_w4(const float* __restrict__ wihf, const float* __restrict__ whhf,
                          const float* __restrict__ wihb, const float* __restrict__ whhb,
                          float* __restrict__ w4) {
    size_t total = (size_t)2 * H_ * 4 * KQ_ * 4;
    for (size_t idx = (size_t)blockIdx.x * 256 + threadIdx.x; idx < total;
         idx += (size_t)gridDim.x * 256) {
        int j = (int)(idx & 3);
        size_t t = idx >> 2;
        int k4 = (int)(t % KQ_); t /= KQ_;
        int g = (int)(t & 3); t >>= 2;
        int u = (int)(t % H_);
        int dir = (int)(t / H_);
        int k = k4 * 4 + j;
        int row = g * H_ + u;
        const float* wih = dir ? wihb : wihf;
        const float* whh = dir ? whhb : whhf;
        w4[idx] = (k < I_) ? wih[(size_t)row * I_ + k]
                           : whh[(size_t)row * H_ + (k - I_)];
    }
}

// x[b][s][i] -> xt4[s][i4][b][4]; rev variant gathers per-batch reversed rows.
__global__ __launch_bounds__(256) void k_xpose4(const float* __restrict__ x,
                                                const int* __restrict__ len,
                                                float* __restrict__ xt4,
                                                float* __restrict__ xrt4) {
    __shared__ int lsrc[B_];
    int s = blockIdx.x & 511, isrev = blockIdx.x >> 9;  // grid = 1024
    int tid = threadIdx.x;
    if (tid < B_) {
        int src = s;
        if (isrev) { int L = len[tid]; src = (s < L) ? (L - 1 - s) : s; }
        lsrc[tid] = src;
    }
    __syncthreads();
    float* dst = (isrev ? xrt4 : xt4) + (size_t)s * I_ * B_;
    for (int dw = tid; dw < I_ * B_; dw += 256) {
        int i4 = dw >> 8;          // / 256
        int r = dw & 255;
        int b = r >> 2, j = r & 3;
        int i = i4 * 4 + j;
        dst[dw] = x[((size_t)b * S_ + lsrc[b]) * I_ + i];
    }
}

// ---------------- persistent BiLSTM scan, flag-based sync ----------------
// 256 blocks x 512 threads (cooperative launch for co-residency; NO grid.sync).
// Block = (dir, ug) owns units u = ug*4+0..3. Wave wq handles k4 = wq mod 8.
// Weights/x: normal cached loads -> L1/L2-resident across all 512 steps.
// h exchange: __hip_atomic_{load,store} RELAXED/AGENT, layout [dir][u][b]
// (finalize wave stores one contiguous 256B full-line run; consumer loads
// are coalesced per-unit). Arrival: per-dir IF counter after vmcnt(0) drain
// + block barrier. ONLY wave 0 polls (1 coalesced request per poll, s_sleep
// backoff); other waves sleep at __syncthreads until release.
__global__ __launch_bounds__(512) void k_scan(
    const float* __restrict__ w4,
    const float* __restrict__ xt4, const float* __restrict__ xrt4,
    float* __restrict__ ha, float* __restrict__ hb,
    float* __restrict__ yf, float* __restrict__ ybr,
    const float* __restrict__ bf, const float* __restrict__ bb,
    const int* __restrict__ len, int* __restrict__ cnt) {
    __shared__ float parts[8 * 16 * B_];   // 32 KB
    const int dir = blockIdx.x >> 7;
    const int ug  = blockIdx.x & 127;
    const int tid = threadIdx.x;
    const int lane = tid & 63;
    const int wq = __builtin_amdgcn_readfirstlane(tid >> 6);  // 0..7

    const float4* __restrict__ wv = (const float4*)w4;
    const size_t wbase = (((size_t)dir * H_ + (ug << 2)) * 4) * KQ_;
    const float4* __restrict__ xall = (const float4*)(dir ? xrt4 : xt4);
    float* __restrict__ ybase = dir ? ybr : yf;
    int* const cn = cnt + dir * 32;     // 128 B apart

    // finalizer (waves 0..3) persistent state
    const int uF = (ug << 2) + wq;      // valid when wq<4
    float c_reg = 0.f, h_reg = 0.f;
    float bi0 = 0.f, bi1 = 0.f, bi2 = 0.f, bi3 = 0.f;
    if (wq < 4) {
        const float* bias = dir ? bb : bf;
        bi0 = bias[uF]; bi1 = bias[H_ + uF];
        bi2 = bias[2 * H_ + uF]; bi3 = bias[3 * H_ + uF];
    }
    const int Lb = len[lane];

    // first strided k4 >= IQ_ for this wave
    const int k4h0 = wq + (((IQ_ - wq + 7) >> 3) << 3);

    for (int s = 0; s < S_; ++s) {
        const float4* __restrict__ xa4 = xall + (size_t)s * IQ_ * B_ + lane;
        float acc[16];
#pragma unroll
        for (int i = 0; i < 16; ++i) acc[i] = 0.f;

        // ---- x-part (h-independent): runs before the wait ----
        for (int k4 = wq; k4 < IQ_; k4 += 8) {
            float4 a = xa4[(size_t)k4 * B_];
#pragma unroll
            for (int r = 0; r < 16; ++r) {
                float4 w = wv[wbase + (size_t)r * KQ_ + k4];
                acc[r] += a.x * w.x + a.y * w.y + a.z * w.z + a.w * w.w;
            }
        }

        // ---- wait for all h of step s-1: wave 0 polls, barrier releases ----
        if (s) {
            if (wq == 0) {
                const int want = 128 * s;
                while (__hip_atomic_load(cn, __ATOMIC_RELAXED,
                                         __HIP_MEMORY_SCOPE_AGENT) < want)
                    __builtin_amdgcn_s_sleep(2);
            }
            __syncthreads();
        }

        // ---- h-part: coherent loads, layout [dir][u][b] ----
        const int* __restrict__ hbase =
            (const int*)((s & 1) ? hb : ha) + (size_t)dir * H_ * B_ + lane;
        for (int k4 = k4h0; k4 < KQ_; k4 += 8) {
            const int u0 = (k4 - IQ_) << 2;
            int q0 = __hip_atomic_load(hbase + (size_t)(u0 + 0) * B_,
                                       __ATOMIC_RELAXED, __HIP_MEMORY_SCOPE_AGENT);
            int q1 = __hip_atomic_load(hbase + (size_t)(u0 + 1) * B_,
                                       __ATOMIC_RELAXED, __HIP_MEMORY_SCOPE_AGENT);
            int q2 = __hip_atomic_load(hbase + (size_t)(u0 + 2) * B_,
                                       __ATOMIC_RELAXED, __HIP_MEMORY_SCOPE_AGENT);
            int q3 = __hip_atomic_load(hbase + (size_t)(u0 + 3) * B_,
                                       __ATOMIC_RELAXED, __HIP_MEMORY_SCOPE_AGENT);
            float ax = __int_as_float(q0), ay = __int_as_float(q1);
            float az = __int_as_float(q2), aw = __int_as_float(q3);
#pragma unroll
            for (int r = 0; r < 16; ++r) {
                float4 w = wv[wbase + (size_t)r * KQ_ + k4];
                acc[r] += ax * w.x + ay * w.y + az * w.z + aw * w.w;
            }
        }

        // ---- combine partials ----
#pragma unroll
        for (int r = 0; r < 16; ++r) parts[(wq * 16 + r) * B_ + lane] = acc[r];
        __syncthreads();

        float y_val = 0.f;
        if (wq < 4) {
            float g0 = bi0, g1 = bi1, g2 = bi2, g3 = bi3;
#pragma unroll
            for (int w = 0; w < 8; ++w) {
                const float* pw = &parts[(w * 16 + wq * 4) * B_ + lane];
                g0 += pw[0 * B_]; g1 += pw[1 * B_];
                g2 += pw[2 * B_]; g3 += pw[3 * B_];
            }
            const bool valid = (s < Lb);
            float ii = 1.f / (1.f + expf(-g0));
            float ff = 1.f / (1.f + expf(-g1));
            float gg = tanhf(g2);
            float oo = 1.f / (1.f + expf(-g3));
            float cn2 = ff * c_reg + ii * gg;
            float hn = oo * tanhf(cn2);
            if (valid) { c_reg = cn2; h_reg = hn; }
            y_val = valid ? hn : 0.f;
            // contiguous full-line store: [dir][u][b]
            int* hdst = (int*)((s & 1) ? ha : hb) +
                        (size_t)dir * H_ * B_ + ((size_t)uF << 6) + lane;
            __hip_atomic_store(hdst, __float_as_int(h_reg),
                               __ATOMIC_RELAXED, __HIP_MEMORY_SCOPE_AGENT);
        }

        // drain h-store, block barrier, one arrival RMW; y-store off-path.
        asm volatile("s_waitcnt vmcnt(0)" ::: "memory");
        __syncthreads();
        if (tid == 0)
            __hip_atomic_fetch_add(cn, 1, __ATOMIC_RELAXED,
                                   __HIP_MEMORY_SCOPE_AGENT);
        if (wq < 4)
            ybase[(((size_t)s * H_ + uF) << 6) + lane] = y_val;
    }
}

// ---------------- logits / CRF epilogue ----------------
__global__ __launch_bounds__(256) void k_logits(const float* __restrict__ yf,
                                                const float* __restrict__ ybr,
                                                const float* __restrict__ wc,
                                                const float* __restrict__ bcv,
                                                float* __restrict__ L1,
                                                float* __restrict__ L2p) {
    __shared__ float smem[T_ * H_];
    int part = blockIdx.x >> 9;
    int s = blockIdx.x & 511;
    int tid = threadIdx.x;
    const float* y = part ? ybr : yf;
    float* Ldst = part ? L2p : L1;
    for (int idx = tid; idx < T_ * H_; idx += 256) {
        int t = idx >> 9;
        int h = idx & 511;
        smem[idx] = wc[(size_t)t * 1024 + part * 512 + h];
    }
    __syncthreads();
    int q = tid >> 6, b = tid & 63;
    float acc[T_];
#pragma unroll
    for (int t = 0; t < T_; ++t) acc[t] = 0.f;
    const float* yrow = y + (size_t)s * H_ * B_ + b;
    for (int h = q * 128; h < q * 128 + 128; ++h) {
        float a = yrow[(size_t)h * B_];
#pragma unroll
        for (int t = 0; t < T_; ++t) acc[t] += a * smem[t * H_ + h];
    }
    __syncthreads();
    float* pl = smem;
#pragma unroll
    for (int t = 0; t < T_; ++t) pl[(q * 64 + b) * 26 + t] = acc[t];
    __syncthreads();
    for (int idx = tid; idx < B_ * T_; idx += 256) {
        int bb2 = idx / T_;
        int t = idx - bb2 * T_;
        float v = pl[(0 * 64 + bb2) * 26 + t] + pl[(1 * 64 + bb2) * 26 + t] +
                  pl[(2 * 64 + bb2) * 26 + t] + pl[(3 * 64 + bb2) * 26 + t];
        if (!part) v += bcv[t];
        Ldst[((size_t)bb2 * S_ + s) * T_ + t] = v;
    }
}

__global__ void k_combine(const float* __restrict__ L1, const float* __restrict__ L2p,
                          const int* __restrict__ len, float* __restrict__ outlog) {
    int id = blockIdx.x * 256 + threadIdx.x;  // 32768 = B*S
    int b = id >> 9;
    int s = id & 511;
    int L = len[b];
    int sr = (s < L) ? (L - 1 - s) : s;
    const float* p1 = L1 + ((size_t)b * S_ + s) * T_;
    const float* p2 = L2p + ((size_t)b * S_ + sr) * T_;
    float* o = outlog + ((size_t)b * S_ + s) * T_;
#pragma unroll
    for (int t = 0; t < T_; ++t) o[t] = p1[t] + p2[t];
}

__global__ __launch_bounds__(64) void k_crf_nll(const float* __restrict__ em,
                                                const int* __restrict__ labels,
                                                const int* __restrict__ len,
                                                const float* __restrict__ cs,
                                                const float* __restrict__ ce,
                                                const float* __restrict__ ctr,
                                                float* __restrict__ llh) {
    int b = blockIdx.x, tid = threadIdx.x;
    __shared__ float tr[T_ * T_];
    __shared__ float sa[T_], sb[T_];
    for (int idx = tid; idx < T_ * T_; idx += 64) tr[idx] = ctr[idx];
    const float* e = em + (size_t)b * S_ * T_;
    int L = len[b];
    if (tid < T_) sa[tid] = cs[tid] + e[tid];
    __syncthreads();
    float* cur = sa;
    float* nx = sb;
    for (int t = 1; t < L; ++t) {
        if (tid < T_) {
            float m = -1e30f;
            for (int i = 0; i < T_; ++i) m = fmaxf(m, cur[i] + tr[i * T_ + tid]);
            float ssum = 0.f;
            for (int i = 0; i < T_; ++i) ssum += expf(cur[i] + tr[i * T_ + tid] - m);
            nx[tid] = m + logf(ssum) + e[(size_t)t * T_ + tid];
        }
        __syncthreads();
        float* tmp = cur; cur = nx; nx = tmp;
    }
    float part = 0.f;
    for (int t = tid; t < S_; t += 64) {
        if (t >= 1 && t < L) {
            int lp = labels[b * S_ + t - 1];
            int lc = labels[b * S_ + t];
            part += tr[lp * T_ + lc] + e[(size_t)t * T_ + lc];
        }
    }
    for (int off = 32; off; off >>= 1) part += __shfl_down(part, off, 64);
    if (tid == 0) {
        float m = -1e30f;
        for (int j = 0; j < T_; ++j) m = fmaxf(m, cur[j] + ce[j]);
        float ssum = 0.f;
        for (int j = 0; j < T_; ++j) ssum += expf(cur[j] + ce[j] - m);
        float denom = m + logf(ssum);
        int l0 = labels[b * S_];
        int lL = labels[b * S_ + L - 1];
        float num = cs[l0] + e[l0] + part + ce[lL];
        llh[b] = num - denom;
    }
}

__global__ void k_loss(const float* __restrict__ llh, const int* __restrict__ len,
                       float* __restrict__ out0) {
    int tid = threadIdx.x;
    float v = llh[tid];
    float n = (float)len[tid];
    for (int off = 32; off; off >>= 1) {
        v += __shfl_down(v, off, 64);
        n += __shfl_down(n, off, 64);
    }
    if (tid == 0) out0[0] = -(v / n);
}

__global__ __launch_bounds__(64) void k_viterbi(const float* __restrict__ em,
                                                const int* __restrict__ len,
                                                const float* __restrict__ cs,
                                                const float* __restrict__ ce,
                                                const float* __restrict__ ctr,
                                                float* __restrict__ otags,
                                                float* __restrict__ omask) {
    int b = blockIdx.x, tid = threadIdx.x;
    __shared__ float tr[T_ * T_];
    __shared__ float sa[T_], sb[T_];
    __shared__ unsigned char hist[(S_ - 1) * T_];
    __shared__ unsigned char tg[S_];
    for (int idx = tid; idx < T_ * T_; idx += 64) tr[idx] = ctr[idx];
    const float* e = em + (size_t)b * S_ * T_;
    int L = len[b];
    if (tid < T_) sa[tid] = cs[tid] + e[tid];
    __syncthreads();
    float* cur = sa;
    float* nx = sb;
    for (int t = 1; t < L; ++t) {
        if (tid < T_) {
            float best = -1e30f;
            int bi = 0;
            for (int i = 0; i < T_; ++i) {
                float v = cur[i] + tr[i * T_ + tid];
                if (v > best) { best = v; bi = i; }
            }
            nx[tid] = best + e[(size_t)t * T_ + tid];
            hist[(t - 1) * T_ + tid] = (unsigned char)bi;
        }
        __syncthreads();
        float* tmp = cur; cur = nx; nx = tmp;
    }
    if (tid == 0) {
        float best = -1e30f;
        int bt = 0;
        for (int j = 0; j < T_; ++j) {
            float v = cur[j] + ce[j];
            if (v > best) { best = v; bt = j; }
        }
        tg[S_ - 1] = (unsigned char)bt;
        for (int t = S_ - 2; t >= 0; --t) {
            if (t + 1 < L) bt = hist[t * T_ + bt];
            tg[t] = (unsigned char)bt;
        }
    }
    __syncthreads();
    for (int idx = tid; idx < S_; idx += 64) {
        otags[(size_t)b * S_ + idx] = (float)tg[idx];
        omask[(size_t)b * S_ + idx] = (idx < L) ? 1.f : 0.f;
    }
}

// ---------------- host launch ----------------
extern "C" void kernel_launch(void* const* d_in, const int* in_sizes, int n_in,
                              void* d_out, int out_size, void* d_ws, size_t ws_size,
                              hipStream_t stream) {
    const float* x    = (const float*)d_in[0];
    const float* wihf = (const float*)d_in[1];
    const float* whhf = (const float*)d_in[2];
    const float* bf   = (const float*)d_in[3];
    const float* wihb = (const float*)d_in[4];
    const float* whhb = (const float*)d_in[5];
    const float* bb   = (const float*)d_in[6];
    const float* wc   = (const float*)d_in[7];
    const float* bc   = (const float*)d_in[8];
    const float* cs   = (const float*)d_in[9];
    const float* ce   = (const float*)d_in[10];
    const float* ctr  = (const float*)d_in[11];
    const int* am     = (const int*)d_in[12];
    const int* labels = (const int*)d_in[13];

    float* ws   = (float*)d_ws;
    float* xt4  = ws + OFS_XT;
    float* xrt4 = ws + OFS_XRT;
    float* w4   = ws + OFS_WC;
    float* h4a  = ws + OFS_H0;
    float* h4b  = ws + OFS_H1;
    float* yf   = ws + OFS_YF;
    float* ybr  = ws + OFS_YB;
    float* L1p  = ws + OFS_L1;
    float* L2p  = ws + OFS_L2;
    int*   lenp = (int*)(ws + OFS_LEN);
    float* llhp = ws + OFS_LLH;
    int*   cntp = (int*)(ws + OFS_CNT);
    float* out  = (float*)d_out;

    k_lengths<<<1, 64, 0, stream>>>(am, lenp);
    k_prep_w4<<<2048, 256, 0, stream>>>(wihf, whhf, wihb, whhb, w4);
    k_zero<<<512, 256, 0, stream>>>(h4a, 2 * 2 * H_ * B_);  // h4a, h4b
    k_zero<<<1, 64, 0, stream>>>(ws + OFS_CNT, 64);          // counters
    k_xpose4<<<1024, 256, 0, stream>>>(x, lenp, xt4, xrt4);

    {
        void* kargs[] = {
            (void*)&w4, (void*)&xt4, (void*)&xrt4,
            (void*)&h4a, (void*)&h4b,
            (void*)&yf, (void*)&ybr,
            (void*)&bf, (void*)&bb,
            (void*)&lenp, (void*)&cntp
        };
        hipLaunchCooperativeKernel((const void*)k_scan,
                                   dim3(256), dim3(512), kargs, 0, stream);
    }

    k_logits<<<1024, 256, 0, stream>>>(yf, ybr, wc, bc, L1p, L2p);
    k_combine<<<128, 256, 0, stream>>>(L1p, L2p, lenp, out + OFF_LOGITS);
    k_crf_nll<<<64, 64, 0, stream>>>(out + OFF_LOGITS, labels, lenp, cs, ce, ctr, llhp);
    k_loss<<<1, 64, 0, stream>>>(llhp, lenp, out);
    k_viterbi<<<64, 64, 0, stream>>>(out + OFF_LOGITS, lenp, cs, ce, ctr,
                                     out + OFF_TAGS, out + OFF_MASK);
}